// Round 16
// baseline (453.873 us; speedup 1.0000x reference)
//
#include <hip/hip_runtime.h>
#include <hip/hip_bf16.h>

#define NB 16
#define N2V 618
#define N3V 2466
#define FEAT 963
#define HID 192
#define IN_DIM 1163
#define KPAD2 1216         // 1163 padded to 38*32
#define ETILES 38
#define EHALF 19
#define MTOT (NB * N3V)    // 39456
#define M2   (NB * N2V)    // 9888

typedef __attribute__((ext_vector_type(8))) short bf16x8;
typedef __attribute__((ext_vector_type(4))) float f32x4;

__device__ __forceinline__ float bf2f(ushort u) {
    return __uint_as_float(((unsigned)u) << 16);
}
__device__ __forceinline__ ushort f2bf(float f) {   // round-to-nearest-even
    unsigned u = __float_as_uint(f);
    return (ushort)((u + 0x7FFFu + ((u >> 16) & 1u)) >> 16);
}
// bijective XCD-chunk swizzle (m204)
__device__ __forceinline__ int xcd_swz(int bid, int G) {
    int q = G >> 3, r = G & 7;
    int xcd = bid & 7, slot = bid >> 3;
    return (xcd < r) ? xcd * (q + 1) + slot : r * (q + 1) + (xcd - r) * q + slot;
}

// ---------------------------------------------------------------------------
// fused qkv + attention: block = (batch, 16 queries); 624 blocks.
// ---------------------------------------------------------------------------
__global__ __launch_bounds__(256) void attn_fused(
    const float* __restrict__ x2,
    const float* __restrict__ Wq, const float* __restrict__ bq,
    const float* __restrict__ Wk, const float* __restrict__ bk,
    const float* __restrict__ Wv, const float* __restrict__ bv,
    float* __restrict__ att)
{
    __shared__ float4 kv[N2V * 4];            // K: [0,2*N2V), V: [2*N2V,4*N2V)
    int b = blockIdx.x, qb = blockIdx.y;
    const float* x2b = x2 + (size_t)b * N2V * 3;

    for (int i = threadIdx.x; i < N2V; i += 256) {
        float c0 = x2b[i * 3], c1 = x2b[i * 3 + 1], c2 = x2b[i * 3 + 2];
        float kk[8], vv[8];
#pragma unroll
        for (int d = 0; d < 8; ++d) {
            kk[d] = bk[d] + c0 * Wk[8 + d] + c1 * Wk[16 + d] + c2 * Wk[24 + d];
            vv[d] = bv[d] + c0 * Wv[8 + d] + c1 * Wv[16 + d] + c2 * Wv[24 + d];
        }
        kv[i * 2]     = (float4){kk[0], kk[1], kk[2], kk[3]};
        kv[i * 2 + 1] = (float4){kk[4], kk[5], kk[6], kk[7]};
        kv[N2V * 2 + i * 2]     = (float4){vv[0], vv[1], vv[2], vv[3]};
        kv[N2V * 2 + i * 2 + 1] = (float4){vv[4], vv[5], vv[6], vv[7]};
    }
    __syncthreads();

    int ql = threadIdx.x >> 4, sub = threadIdx.x & 15;
    int qi = qb * 16 + ql;
    bool valid = qi < N2V;
    float qv[8];
#pragma unroll
    for (int d = 0; d < 8; ++d) qv[d] = 0.f;
    if (valid) {
        float c0 = x2b[qi * 3], c1 = x2b[qi * 3 + 1], c2 = x2b[qi * 3 + 2];
#pragma unroll
        for (int d = 0; d < 8; ++d)
            qv[d] = bq[d] + c0 * Wq[8 + d] + c1 * Wq[16 + d] + c2 * Wq[24 + d];
    }

    const float scale = 0.35355339059327373f;
    float m = -3.0e38f, lsum = 0.f, acc[8];
#pragma unroll
    for (int d = 0; d < 8; ++d) acc[d] = 0.f;

    for (int kk = sub; kk < N2V; kk += 16) {
        float4 k0 = kv[kk * 2], k1 = kv[kk * 2 + 1];
        float s = qv[0] * k0.x + qv[1] * k0.y + qv[2] * k0.z + qv[3] * k0.w
                + qv[4] * k1.x + qv[5] * k1.y + qv[6] * k1.z + qv[7] * k1.w;
        s *= scale;
        float nm = fmaxf(m, s);
        float corr = __expf(m - nm);
        float p = __expf(s - nm);
        lsum = lsum * corr + p;
        float4 v0 = kv[N2V * 2 + kk * 2], v1 = kv[N2V * 2 + kk * 2 + 1];
        acc[0] = acc[0] * corr + p * v0.x; acc[1] = acc[1] * corr + p * v0.y;
        acc[2] = acc[2] * corr + p * v0.z; acc[3] = acc[3] * corr + p * v0.w;
        acc[4] = acc[4] * corr + p * v1.x; acc[5] = acc[5] * corr + p * v1.y;
        acc[6] = acc[6] * corr + p * v1.z; acc[7] = acc[7] * corr + p * v1.w;
        m = nm;
    }
#pragma unroll
    for (int o = 1; o <= 8; o <<= 1) {
        float m2 = __shfl_xor(m, o);
        float l2 = __shfl_xor(lsum, o);
        float nm = fmaxf(m, m2);
        float c1 = __expf(m - nm), c2 = __expf(m2 - nm);
        lsum = lsum * c1 + l2 * c2;
#pragma unroll
        for (int d = 0; d < 8; ++d) {
            float a2 = __shfl_xor(acc[d], o);
            acc[d] = acc[d] * c1 + a2 * c2;
        }
        m = nm;
    }
    if (valid && sub == 0) {
#pragma unroll
        for (int d = 0; d < 8; ++d)
            att[((size_t)b * N2V + qi) * 8 + d] = acc[d] / lsum;
    }
}

// ---------------------------------------------------------------------------
// merged prep: blocks 0..N3V-1 = adjacency extraction; blocks >= N3V =
// fragment-layout weight transposes (entry + 13 res layers).
// ---------------------------------------------------------------------------
#define ENT_CHUNKS (24 * 38 * 64)
#define RES_CHUNKS (13 * 12 * 12 * 64)
#define WT_BLOCKS ((ENT_CHUNKS + RES_CHUNKS + 255) / 256)
__global__ void prep_all(const float* __restrict__ adj, const int* __restrict__ unpool,
                         int* __restrict__ cols, float* __restrict__ vals,
                         int* __restrict__ eidx, float* __restrict__ ew,
                         int* __restrict__ sidx,
                         const float* __restrict__ W_in, const float* __restrict__ loopW_in,
                         const float* __restrict__ res_W, const float* __restrict__ res_loopW,
                         const float* __restrict__ W_out, const float* __restrict__ loopW_out,
                         ushort* __restrict__ wt_e, ushort* __restrict__ wt_r)
{
    if (blockIdx.x >= N3V) {
        int idx = (blockIdx.x - N3V) * 256 + threadIdx.x;
        if (idx < ENT_CHUNKS) {
            int lane = idx & 63, r = idx >> 6;
            int kt = r % ETILES, ntile = r / ETILES;
            int n = ntile * 16 + (lane & 15);
            int k0 = kt * 32 + (lane >> 4) * 8;
            bf16x8 o;
#pragma unroll
            for (int j = 0; j < 8; ++j) {
                int k = k0 + j;
                float v = 0.f;
                if (k < IN_DIM) v = (n < 192) ? W_in[k * 192 + n] : loopW_in[k * 192 + (n - 192)];
                o[j] = (short)f2bf(v);
            }
            *(bf16x8*)(wt_e + (size_t)idx * 8) = o;
            return;
        }
        idx -= ENT_CHUNKS;
        if (idx >= RES_CHUNKS) return;
        int lane = idx & 63, r = idx >> 6;
        int kt = r % 12; r /= 12;
        int ntile = r % 12; int l = r / 12;
        const float* W = (l < 12) ? (res_W + (size_t)l * 192 * 192) : W_out;
        const float* L = (l < 12) ? (res_loopW + (size_t)l * 192 * 192) : loopW_out;
        int n = ntile * 16 + (lane & 15);
        int k0 = kt * 32 + (lane >> 4) * 8;
        bf16x8 o;
#pragma unroll
        for (int j = 0; j < 8; ++j) {
            int k2 = k0 + j;
            float v = (k2 < 192) ? W[k2 * 192 + n] : L[(k2 - 192) * 192 + n];
            o[j] = (short)f2bf(v);
        }
        *(bf16x8*)(wt_r + (size_t)idx * 8) = o;
        return;
    }

    int m = blockIdx.x;
    __shared__ int cnt;
    __shared__ int lc[8];
    __shared__ float lv[8];
    if (threadIdx.x == 0) cnt = 0;
    __syncthreads();
    for (int c = threadIdx.x; c < N3V; c += 256) {
        float a = adj[(size_t)m * N3V + c];
        if (a != 0.f) {
            int p = atomicAdd(&cnt, 1);
            if (p < 6) { lc[p] = c; lv[p] = a; }
        }
    }
    __syncthreads();
    if (threadIdx.x == 0) {
        int n = cnt < 6 ? cnt : 6;
        for (int i = 1; i < n; ++i) {
            int ci = lc[i]; float vi = lv[i]; int j = i - 1;
            while (j >= 0 && lc[j] > ci) { lc[j + 1] = lc[j]; lv[j + 1] = lv[j]; --j; }
            lc[j + 1] = ci; lv[j + 1] = vi;
        }
        int ne = 0;
        for (int i = 0; i < 6; ++i) {
            int c = (i < n) ? lc[i] : 0;
            float w = (i < n) ? lv[i] : 0.f;
            cols[m * 6 + i] = c;
            vals[m * 6 + i] = w;
            if (i < n) {
                if (c < N2V) { eidx[m * 12 + ne] = c; ew[m * 12 + ne] = w; ++ne; }
                else {
                    int jj = c - N2V;
                    eidx[m * 12 + ne] = unpool[2 * jj];     ew[m * 12 + ne] = 0.5f * w; ++ne;
                    eidx[m * 12 + ne] = unpool[2 * jj + 1]; ew[m * 12 + ne] = 0.5f * w; ++ne;
                }
            }
        }
        for (; ne < 12; ++ne) { eidx[m * 12 + ne] = 0; ew[m * 12 + ne] = 0.f; }
        if (m < N2V) { sidx[m * 2] = m; sidx[m * 2 + 1] = -1; }
        else {
            int j = m - N2V;
            sidx[m * 2] = unpool[2 * j];
            sidx[m * 2 + 1] = unpool[2 * j + 1];
        }
    }
}

// ---------------------------------------------------------------------------
// F in FRAGMENT layout: F3[rt][kt][lane][8]
// ---------------------------------------------------------------------------
__global__ void build_F3(const float* __restrict__ x, const float* __restrict__ xh,
                         const float* __restrict__ att, ushort* __restrict__ F3)
{
    int rt = blockIdx.x;                       // 0..617
    for (int c = threadIdx.x; c < ETILES * 64; c += 256) {
        int kt = c >> 6, lane = c & 63;
        int row = rt * 16 + (lane & 15);
        int k0 = kt * 32 + (lane >> 4) * 8;
        bf16x8 o;
#pragma unroll
        for (int j = 0; j < 8; ++j) {
            int k = k0 + j;
            float v = 0.f;
            if (k < FEAT) v = x[(size_t)row * FEAT + k];
            else if (k < FEAT + HID) v = xh[(size_t)row * HID + (k - FEAT)];
            else if (k < IN_DIM) v = att[(size_t)row * 8 + (k - FEAT - HID)];
            o[j] = (short)f2bf(v);
        }
        *(bf16x8*)(F3 + ((size_t)(rt * ETILES + kt) * 64 + lane) * 8) = o;
    }
}

// ---------------------------------------------------------------------------
// entry GEMM, K-split x2, fragment layout. 512 thr; 64r x 192c; grid (155,2).
// ---------------------------------------------------------------------------
__global__ __launch_bounds__(512) void gemm_entry(
    const ushort* __restrict__ F3, const ushort* __restrict__ Wt,
    ushort* __restrict__ u2)
{
    __shared__ float part[64 * 192];   // 48 KB

    int tid = threadIdx.x;
    int wave = tid >> 6, lane = tid & 63;
    int kh = wave >> 2, w4 = wave & 3;
    int lr = lane & 15, lkq = lane >> 4;
    int row0 = blockIdx.x * 64;
    int rt0 = blockIdx.x * 4;
    int lnb = w4 * 48;
    int nb = blockIdx.y * 192 + lnb;
    int ntile0 = nb >> 4;
    int tbeg = kh * EHALF, tend = tbeg + EHALF;

    int rts[4];
#pragma unroll
    for (int mt = 0; mt < 4; ++mt) {
        int rt = rt0 + mt;
        rts[mt] = (rt < M2 / 16) ? rt : (M2 / 16 - 1);
    }

    f32x4 acc[4][3];
#pragma unroll
    for (int mt = 0; mt < 4; ++mt)
#pragma unroll
        for (int nt = 0; nt < 3; ++nt) acc[mt][nt] = (f32x4){0.f, 0.f, 0.f, 0.f};

    bf16x8 a0[4], b0[3], a1[4], b1[3];
    auto LD = [&](int t, bf16x8 (&a)[4], bf16x8 (&b)[3]) {
#pragma unroll
        for (int mt = 0; mt < 4; ++mt)
            a[mt] = *(const bf16x8*)(F3 + ((size_t)(rts[mt] * ETILES + t) * 64 + lane) * 8);
#pragma unroll
        for (int nt = 0; nt < 3; ++nt)
            b[nt] = *(const bf16x8*)(Wt + ((size_t)((ntile0 + nt) * ETILES + t) * 64 + lane) * 8);
    };
    auto MM = [&](bf16x8 (&a)[4], bf16x8 (&b)[3]) {
#pragma unroll
        for (int mt = 0; mt < 4; ++mt)
#pragma unroll
            for (int nt = 0; nt < 3; ++nt)
                acc[mt][nt] = __builtin_amdgcn_mfma_f32_16x16x32_bf16(a[mt], b[nt], acc[mt][nt], 0, 0, 0);
    };

    LD(tbeg, a0, b0);
    for (int t = tbeg; t < tend; t += 2) {
        if (t + 1 < tend) LD(t + 1, a1, b1);
        MM(a0, b0);
        if (t + 2 < tend) LD(t + 2, a0, b0);
        if (t + 1 < tend) MM(a1, b1);
    }

    int crow = lkq * 4;
    if (kh == 1) {
#pragma unroll
        for (int mt = 0; mt < 4; ++mt)
#pragma unroll
            for (int r = 0; r < 4; ++r)
#pragma unroll
                for (int nt = 0; nt < 3; ++nt)
                    part[(mt * 16 + crow + r) * 192 + lnb + nt * 16 + lr] = acc[mt][nt][r];
    }
    __syncthreads();
    if (kh == 0) {
#pragma unroll
        for (int mt = 0; mt < 4; ++mt)
#pragma unroll
            for (int r = 0; r < 4; ++r) {
                int orow = row0 + mt * 16 + crow + r;
                if (orow < M2) {
#pragma unroll
                    for (int nt = 0; nt < 3; ++nt) {
                        float s = acc[mt][nt][r] + part[(mt * 16 + crow + r) * 192 + lnb + nt * 16 + lr];
                        u2[(size_t)orow * 384 + nb + nt * 16 + lr] = f2bf(s);
                    }
                }
            }
    }
}

// ---------------------------------------------------------------------------
// entry combine: h = relu( sum_i ew*Pw[eidx] + mid(Pl over sidx) + bias )
// ---------------------------------------------------------------------------
__global__ void combine_entry(const ushort* __restrict__ u2, const int* __restrict__ eidx,
                              const float* __restrict__ ew, const int* __restrict__ sidx,
                              const float* __restrict__ bias, ushort* __restrict__ h)
{
    int lb = xcd_swz(blockIdx.x, gridDim.x);
    int tid = threadIdx.x;
    int rloc = tid / 24, f8 = tid % 24;
    int bm = lb * 8 + rloc;
    if (bm >= MTOT) return;
    int b = bm / N3V, n = bm % N3V;
    const ushort* base = u2 + (size_t)b * N2V * 384;

    float acc[8];
#pragma unroll
    for (int e = 0; e < 8; ++e) acc[e] = 0.f;
#pragma unroll
    for (int i = 0; i < 12; ++i) {
        float w = ew[n * 12 + i];
        bf16x8 v = *(const bf16x8*)(base + (size_t)eidx[n * 12 + i] * 384 + f8 * 8);
#pragma unroll
        for (int e = 0; e < 8; ++e) acc[e] += w * bf2f((ushort)v[e]);
    }
    int p0 = sidx[n * 2], p1 = sidx[n * 2 + 1];
    bf16x8 s0 = *(const bf16x8*)(base + (size_t)p0 * 384 + 192 + f8 * 8);
    if (p1 >= 0) {
        bf16x8 s1 = *(const bf16x8*)(base + (size_t)p1 * 384 + 192 + f8 * 8);
#pragma unroll
        for (int e = 0; e < 8; ++e) acc[e] += 0.5f * (bf2f((ushort)s0[e]) + bf2f((ushort)s1[e]));
    } else {
#pragma unroll
        for (int e = 0; e < 8; ++e) acc[e] += bf2f((ushort)s0[e]);
    }
    bf16x8 o;
#pragma unroll
    for (int e = 0; e < 8; ++e)
        o[e] = (short)f2bf(fmaxf(acc[e] + bias[f8 * 8 + e], 0.f));
    *(bf16x8*)(h + (size_t)bm * 192 + f8 * 8) = o;
}

// ---------------------------------------------------------------------------
// fused res GConv, wave-specialized phase 1, ALL-WAVE phase 2:
//   phase 1: waves 4-7 self-half GEMM (2m x 3n) -> f32 partials in LDS;
//            waves 0-3 gather 768 tasks -> gs (XOR-swizzled).  One barrier.
//   phase 2: ALL 8 waves g-half GEMM, wave = (m-tile w>>2) x (col w&3),
//            1m x 3n each; add partials + bias (+residual), store.
// ---------------------------------------------------------------------------
template <int ACT>
__global__ __launch_bounds__(512) void gconv_fused(
    const ushort* __restrict__ src, const int* __restrict__ cols,
    const float* __restrict__ vals, const ushort* __restrict__ Wt,
    const float* __restrict__ bias, const ushort* __restrict__ hprev,
    ushort* __restrict__ outp)
{
    __shared__ ushort gs[32 * 192];    // 12 KB, XOR-swizzled
    __shared__ float part[32 * 192];   // 24 KB

    int lb = xcd_swz(blockIdx.x, gridDim.x);
    int tid = threadIdx.x;
    int row0 = lb * 32;                // MTOT % 32 == 0

    int wave = tid >> 6, lane = tid & 63;
    int w4 = wave & 3, wm = wave >> 2;
    int lr = lane & 15, lkq = lane >> 4, lk = lkq * 8;
    int nb = w4 * 48;
    int ntile0 = nb >> 4;
    int crow = lkq * 4;

    if (wave >= 4) {
        // ---- phase 1 (waves 4-7): self-half GEMM, 2m x 3n, k-tiles 6..11 ----
        int rows[2] = { row0 + lr, row0 + 16 + lr };
        f32x4 acc[2][3];
#pragma unroll
        for (int mt = 0; mt < 2; ++mt)
#pragma unroll
            for (int nt = 0; nt < 3; ++nt) acc[mt][nt] = (f32x4){0.f, 0.f, 0.f, 0.f};

        bf16x8 a0[2], b0[3], a1[2], b1[3];
        auto LDs = [&](int t, bf16x8 (&a)[2], bf16x8 (&b)[3]) {
            int kk = t * 32 + lk;
#pragma unroll
            for (int mt = 0; mt < 2; ++mt)
                a[mt] = *(const bf16x8*)(src + (size_t)rows[mt] * 192 + kk);
#pragma unroll
            for (int nt = 0; nt < 3; ++nt)
                b[nt] = *(const bf16x8*)(Wt + ((size_t)((ntile0 + nt) * 12 + 6 + t) * 64 + lane) * 8);
        };
        auto MMs = [&](bf16x8 (&a)[2], bf16x8 (&b)[3]) {
#pragma unroll
            for (int mt = 0; mt < 2; ++mt)
#pragma unroll
                for (int nt = 0; nt < 3; ++nt)
                    acc[mt][nt] = __builtin_amdgcn_mfma_f32_16x16x32_bf16(a[mt], b[nt], acc[mt][nt], 0, 0, 0);
        };
        LDs(0, a0, b0);
#pragma unroll
        for (int t = 0; t < 6; t += 2) {
            if (t + 1 < 6) LDs(t + 1, a1, b1);
            MMs(a0, b0);
            if (t + 2 < 6) LDs(t + 2, a0, b0);
            if (t + 1 < 6) MMs(a1, b1);
        }
#pragma unroll
        for (int mt = 0; mt < 2; ++mt)
#pragma unroll
            for (int r = 0; r < 4; ++r)
#pragma unroll
                for (int nt = 0; nt < 3; ++nt)
                    part[(mt * 16 + crow + r) * 192 + nb + nt * 16 + lr] = acc[mt][nt][r];
    } else {
        // ---- phase 1 (waves 0-3): gather 768 tasks over threads 0..255 ----
#pragma unroll
        for (int it = 0; it < 3; ++it) {
            int task = tid + it * 256;
            int r = task / 24, f8 = task % 24;
            int bm = row0 + r;
            int b = bm / N3V, m = bm % N3V;
            const ushort* hb = src + (size_t)b * N3V * 192;
            float ga[8];
#pragma unroll
            for (int e = 0; e < 8; ++e) ga[e] = 0.f;
#pragma unroll
            for (int j = 0; j < 6; ++j) {
                float w = vals[m * 6 + j];
                bf16x8 v = *(const bf16x8*)(hb + (size_t)cols[m * 6 + j] * 192 + f8 * 8);
#pragma unroll
                for (int e = 0; e < 8; ++e) ga[e] += w * bf2f((ushort)v[e]);
            }
            bf16x8 o;
#pragma unroll
            for (int e = 0; e < 8; ++e) o[e] = (short)f2bf(ga[e]);
            int byte = r * 384 + f8 * 16;
            byte ^= (r & 7) << 4;
            *(bf16x8*)((char*)gs + byte) = o;
        }
    }
    __syncthreads();

    // ---- phase 2 (ALL 8 waves): g-half GEMM, m-tile wm, cols nb ----
    {
        f32x4 acc2[3];
#pragma unroll
        for (int nt = 0; nt < 3; ++nt) acc2[nt] = (f32x4){0.f, 0.f, 0.f, 0.f};

        bf16x8 a0, b0[3], a1, b1[3];
        auto LDg = [&](int t, bf16x8 &a, bf16x8 (&b)[3]) {
            int rr = wm * 16 + lr;
            int byte = rr * 384 + t * 64 + lkq * 16;
            byte ^= (rr & 7) << 4;
            a = *(const bf16x8*)((const char*)gs + byte);
#pragma unroll
            for (int nt = 0; nt < 3; ++nt)
                b[nt] = *(const bf16x8*)(Wt + ((size_t)((ntile0 + nt) * 12 + t) * 64 + lane) * 8);
        };
        auto MMg = [&](bf16x8 &a, bf16x8 (&b)[3]) {
#pragma unroll
            for (int nt = 0; nt < 3; ++nt)
                acc2[nt] = __builtin_amdgcn_mfma_f32_16x16x32_bf16(a, b[nt], acc2[nt], 0, 0, 0);
        };
        LDg(0, a0, b0);
#pragma unroll
        for (int t = 0; t < 6; t += 2) {
            if (t + 1 < 6) LDg(t + 1, a1, b1);
            MMg(a0, b0);
            if (t + 2 < 6) LDg(t + 2, a0, b0);
            if (t + 1 < 6) MMg(a1, b1);
        }

#pragma unroll
        for (int r = 0; r < 4; ++r) {
            int orow = row0 + wm * 16 + crow + r;
#pragma unroll
            for (int nt = 0; nt < 3; ++nt) {
                int nn = nb + nt * 16 + lr;
                float s = acc2[nt][r] + part[(wm * 16 + crow + r) * 192 + nn] + bias[nn];
                s = fmaxf(s, 0.f);
                if (ACT) s = 0.5f * (bf2f(hprev[(size_t)orow * 192 + nn]) + s);
                outp[(size_t)orow * 192 + nn] = f2bf(s);
            }
        }
    }
}

// ---------------------------------------------------------------------------
// fused final head: out[bm][c] = sum_j vals[j]*(y[col_j]@Wg)[c]
//                              + (y[bm]@loopWg)[c] + bg[c]
// block = 64 rows x 4 subs; sub s covers k in [48s,48s+48); quad shfl reduce.
// ---------------------------------------------------------------------------
__global__ void head_fused(const ushort* __restrict__ y, const int* __restrict__ cols,
                           const float* __restrict__ vals, const float* __restrict__ Wg,
                           const float* __restrict__ loopWg, const float* __restrict__ bg,
                           float* __restrict__ out)
{
    int tid = threadIdx.x;
    int rloc = tid >> 2, sub = tid & 3;
    int bm = blockIdx.x * 64 + rloc;
    if (bm >= MTOT) return;
    int b = bm / N3V, m = bm % N3V;
    const ushort* yb = y + (size_t)b * N3V * 192;

    float s[3] = {0.f, 0.f, 0.f};
    // self term: y[bm] @ loopWg
#pragma unroll
    for (int kk = 0; kk < 6; ++kk) {
        int kg = sub * 6 + kk;
        bf16x8 v = *(const bf16x8*)(yb + (size_t)m * 192 + kg * 8);
#pragma unroll
        for (int e = 0; e < 8; ++e) {
            float f = bf2f((ushort)v[e]);
            int k = kg * 8 + e;
            s[0] += f * loopWg[k * 3 + 0];
            s[1] += f * loopWg[k * 3 + 1];
            s[2] += f * loopWg[k * 3 + 2];
        }
    }
    // neighbor terms: vals[j] * (y[col_j] @ Wg)
#pragma unroll
    for (int j = 0; j < 6; ++j) {
        float w = vals[m * 6 + j];
        const ushort* yr = yb + (size_t)cols[m * 6 + j] * 192;
        float t0 = 0.f, t1 = 0.f, t2 = 0.f;
#pragma unroll
        for (int kk = 0; kk < 6; ++kk) {
            int kg = sub * 6 + kk;
            bf16x8 v = *(const bf16x8*)(yr + kg * 8);
#pragma unroll
            for (int e = 0; e < 8; ++e) {
                float f = bf2f((ushort)v[e]);
                int k = kg * 8 + e;
                t0 += f * Wg[k * 3 + 0];
                t1 += f * Wg[k * 3 + 1];
                t2 += f * Wg[k * 3 + 2];
            }
        }
        s[0] += w * t0; s[1] += w * t1; s[2] += w * t2;
    }
#pragma unroll
    for (int o = 1; o <= 2; o <<= 1)
#pragma unroll
        for (int c = 0; c < 3; ++c) s[c] += __shfl_xor(s[c], o);
    if (sub == 0) {
#pragma unroll
        for (int c = 0; c < 3; ++c) out[(size_t)bm * 3 + c] = s[c] + bg[c];
    }
}

// ---------------------------------------------------------------------------
extern "C" void kernel_launch(void* const* d_in, const int* in_sizes, int n_in,
                              void* d_out, int out_size, void* d_ws, size_t ws_size,
                              hipStream_t stream)
{
    const float* x        = (const float*)d_in[0];
    const float* x2       = (const float*)d_in[1];
    const float* xh       = (const float*)d_in[2];
    const float* Wq       = (const float*)d_in[3];
    const float* bq       = (const float*)d_in[4];
    const float* Wk       = (const float*)d_in[5];
    const float* bk       = (const float*)d_in[6];
    const float* Wv       = (const float*)d_in[7];
    const float* bv       = (const float*)d_in[8];
    const float* adj      = (const float*)d_in[9];
    const int*   unpool   = (const int*)d_in[10];
    const float* W_in     = (const float*)d_in[11];
    const float* loopW_in = (const float*)d_in[12];
    const float* b_in     = (const float*)d_in[13];
    const float* res_W    = (const float*)d_in[14];
    const float* res_loopW= (const float*)d_in[15];
    const float* res_b    = (const float*)d_in[16];
    const float* W_out    = (const float*)d_in[17];
    const float* loopW_out= (const float*)d_in[18];
    const float* b_out    = (const float*)d_in[19];
    const float* Wg       = (const float*)d_in[20];
    const float* loopWg   = (const float*)d_in[21];
    const float* bg       = (const float*)d_in[22];
    float* out = (float*)d_out;

    char* ws = (char*)d_ws;
    size_t o = 0;
    auto alloc = [&](size_t bytes) { char* p = ws + o; o += (bytes + 255) & ~(size_t)255; return p; };
    float*  att  = (float*)alloc((size_t)M2 * 8 * 4);
    int*    cols = (int*)alloc((size_t)N3V * 6 * 4);
    float*  vals = (float*)alloc((size_t)N3V * 6 * 4);
    int*    eidx = (int*)alloc((size_t)N3V * 12 * 4);
    float*  ewgt = (float*)alloc((size_t)N3V * 12 * 4);
    int*    sidx = (int*)alloc((size_t)N3V * 2 * 4);
    ushort* F3   = (ushort*)alloc((size_t)M2 * KPAD2 * 2);
    ushort* wt_e = (ushort*)alloc((size_t)ENT_CHUNKS * 8 * 2);
    ushort* wt_r = (ushort*)alloc((size_t)RES_CHUNKS * 8 * 2);
    ushort* u2   = (ushort*)alloc((size_t)M2 * 384 * 2);
    ushort* h    = (ushort*)alloc((size_t)MTOT * 192 * 2);
    ushort* h2   = (ushort*)alloc((size_t)MTOT * 192 * 2);
    ushort* y    = (ushort*)alloc((size_t)MTOT * 192 * 2);
    if (ws_size < o) return;

    attn_fused<<<dim3(NB, 39), 256, 0, stream>>>(x2, Wq, bq, Wk, bk, Wv, bv, att);
    prep_all<<<N3V + WT_BLOCKS, 256, 0, stream>>>(adj, unpool, cols, vals, eidx, ewgt, sidx,
        W_in, loopW_in, res_W, res_loopW, W_out, loopW_out, wt_e, wt_r);
    build_F3<<<M2 / 16, 256, 0, stream>>>(x, xh, att, F3);

    // entry: u2 = F @ [W_in | loopW_in]   (M=9888, K=1216, k-split x2)
    gemm_entry<<<dim3((M2 + 63) / 64, 2), 512, 0, stream>>>(F3, wt_e, u2);
    combine_entry<<<(MTOT + 7) / 8, 192, 0, stream>>>(u2, eidx, ewgt, sidx, b_in, h);

    int gg = MTOT / 32;              // 1233
    ushort* cur = h;
    ushort* nxt = h2;
    for (int i = 0; i < 6; ++i) {
        const float* B0 = res_b + (size_t)(i * 2 + 0) * 192;
        const float* B1 = res_b + (size_t)(i * 2 + 1) * 192;
        const ushort* W0 = wt_r + (size_t)(i * 2 + 0) * (12 * 12 * 64 * 8);
        const ushort* W1 = wt_r + (size_t)(i * 2 + 1) * (12 * 12 * 64 * 8);
        gconv_fused<0><<<gg, 512, 0, stream>>>(cur, cols, vals, W0, B0, nullptr, y);
        gconv_fused<1><<<gg, 512, 0, stream>>>(y, cols, vals, W1, B1, cur, nxt);
        ushort* tmp = cur; cur = nxt; nxt = tmp;
    }

    // out conv (relu)
    gconv_fused<0><<<gg, 512, 0, stream>>>(cur, cols, vals,
        wt_r + (size_t)12 * (12 * 12 * 64 * 8), b_out, nullptr, y);

    head_fused<<<(MTOT + 63) / 64, 256, 0, stream>>>(y, cols, vals, Wg, loopWg, bg, out);
}

// Round 17
// 434.203 us; speedup vs baseline: 1.0453x; 1.0453x over previous
//
#include <hip/hip_runtime.h>
#include <hip/hip_bf16.h>

#define NB 16
#define N2V 618
#define N3V 2466
#define FEAT 963
#define HID 192
#define IN_DIM 1163
#define KPAD2 1216         // 1163 padded to 38*32
#define ETILES 38
#define EHALF 19
#define MTOT (NB * N3V)    // 39456
#define M2   (NB * N2V)    // 9888

typedef __attribute__((ext_vector_type(8))) short bf16x8;
typedef __attribute__((ext_vector_type(4))) float f32x4;

__device__ __forceinline__ float bf2f(ushort u) {
    return __uint_as_float(((unsigned)u) << 16);
}
__device__ __forceinline__ ushort f2bf(float f) {   // round-to-nearest-even
    unsigned u = __float_as_uint(f);
    return (ushort)((u + 0x7FFFu + ((u >> 16) & 1u)) >> 16);
}
// bijective XCD-chunk swizzle (m204)
__device__ __forceinline__ int xcd_swz(int bid, int G) {
    int q = G >> 3, r = G & 7;
    int xcd = bid & 7, slot = bid >> 3;
    return (xcd < r) ? xcd * (q + 1) + slot : r * (q + 1) + (xcd - r) * q + slot;
}

// ---------------------------------------------------------------------------
// fused qkv + attention: block = (batch, 16 queries); 624 blocks.
// ---------------------------------------------------------------------------
__global__ __launch_bounds__(256) void attn_fused(
    const float* __restrict__ x2,
    const float* __restrict__ Wq, const float* __restrict__ bq,
    const float* __restrict__ Wk, const float* __restrict__ bk,
    const float* __restrict__ Wv, const float* __restrict__ bv,
    float* __restrict__ att)
{
    __shared__ float4 kv[N2V * 4];            // K: [0,2*N2V), V: [2*N2V,4*N2V)
    int b = blockIdx.x, qb = blockIdx.y;
    const float* x2b = x2 + (size_t)b * N2V * 3;

    for (int i = threadIdx.x; i < N2V; i += 256) {
        float c0 = x2b[i * 3], c1 = x2b[i * 3 + 1], c2 = x2b[i * 3 + 2];
        float kk[8], vv[8];
#pragma unroll
        for (int d = 0; d < 8; ++d) {
            kk[d] = bk[d] + c0 * Wk[8 + d] + c1 * Wk[16 + d] + c2 * Wk[24 + d];
            vv[d] = bv[d] + c0 * Wv[8 + d] + c1 * Wv[16 + d] + c2 * Wv[24 + d];
        }
        kv[i * 2]     = (float4){kk[0], kk[1], kk[2], kk[3]};
        kv[i * 2 + 1] = (float4){kk[4], kk[5], kk[6], kk[7]};
        kv[N2V * 2 + i * 2]     = (float4){vv[0], vv[1], vv[2], vv[3]};
        kv[N2V * 2 + i * 2 + 1] = (float4){vv[4], vv[5], vv[6], vv[7]};
    }
    __syncthreads();

    int ql = threadIdx.x >> 4, sub = threadIdx.x & 15;
    int qi = qb * 16 + ql;
    bool valid = qi < N2V;
    float qv[8];
#pragma unroll
    for (int d = 0; d < 8; ++d) qv[d] = 0.f;
    if (valid) {
        float c0 = x2b[qi * 3], c1 = x2b[qi * 3 + 1], c2 = x2b[qi * 3 + 2];
#pragma unroll
        for (int d = 0; d < 8; ++d)
            qv[d] = bq[d] + c0 * Wq[8 + d] + c1 * Wq[16 + d] + c2 * Wq[24 + d];
    }

    const float scale = 0.35355339059327373f;
    float m = -3.0e38f, lsum = 0.f, acc[8];
#pragma unroll
    for (int d = 0; d < 8; ++d) acc[d] = 0.f;

    for (int kk = sub; kk < N2V; kk += 16) {
        float4 k0 = kv[kk * 2], k1 = kv[kk * 2 + 1];
        float s = qv[0] * k0.x + qv[1] * k0.y + qv[2] * k0.z + qv[3] * k0.w
                + qv[4] * k1.x + qv[5] * k1.y + qv[6] * k1.z + qv[7] * k1.w;
        s *= scale;
        float nm = fmaxf(m, s);
        float corr = __expf(m - nm);
        float p = __expf(s - nm);
        lsum = lsum * corr + p;
        float4 v0 = kv[N2V * 2 + kk * 2], v1 = kv[N2V * 2 + kk * 2 + 1];
        acc[0] = acc[0] * corr + p * v0.x; acc[1] = acc[1] * corr + p * v0.y;
        acc[2] = acc[2] * corr + p * v0.z; acc[3] = acc[3] * corr + p * v0.w;
        acc[4] = acc[4] * corr + p * v1.x; acc[5] = acc[5] * corr + p * v1.y;
        acc[6] = acc[6] * corr + p * v1.z; acc[7] = acc[7] * corr + p * v1.w;
        m = nm;
    }
#pragma unroll
    for (int o = 1; o <= 8; o <<= 1) {
        float m2 = __shfl_xor(m, o);
        float l2 = __shfl_xor(lsum, o);
        float nm = fmaxf(m, m2);
        float c1 = __expf(m - nm), c2 = __expf(m2 - nm);
        lsum = lsum * c1 + l2 * c2;
#pragma unroll
        for (int d = 0; d < 8; ++d) {
            float a2 = __shfl_xor(acc[d], o);
            acc[d] = acc[d] * c1 + a2 * c2;
        }
        m = nm;
    }
    if (valid && sub == 0) {
#pragma unroll
        for (int d = 0; d < 8; ++d)
            att[((size_t)b * N2V + qi) * 8 + d] = acc[d] / lsum;
    }
}

// ---------------------------------------------------------------------------
// merged prep: blocks 0..N3V-1 = adjacency extraction; blocks >= N3V =
// fragment-layout weight transposes (entry + 13 res layers).
// ---------------------------------------------------------------------------
#define ENT_CHUNKS (24 * 38 * 64)
#define RES_CHUNKS (13 * 12 * 12 * 64)
#define WT_BLOCKS ((ENT_CHUNKS + RES_CHUNKS + 255) / 256)
__global__ void prep_all(const float* __restrict__ adj, const int* __restrict__ unpool,
                         int* __restrict__ cols, float* __restrict__ vals,
                         int* __restrict__ eidx, float* __restrict__ ew,
                         int* __restrict__ sidx,
                         const float* __restrict__ W_in, const float* __restrict__ loopW_in,
                         const float* __restrict__ res_W, const float* __restrict__ res_loopW,
                         const float* __restrict__ W_out, const float* __restrict__ loopW_out,
                         ushort* __restrict__ wt_e, ushort* __restrict__ wt_r)
{
    if (blockIdx.x >= N3V) {
        int idx = (blockIdx.x - N3V) * 256 + threadIdx.x;
        if (idx < ENT_CHUNKS) {
            int lane = idx & 63, r = idx >> 6;
            int kt = r % ETILES, ntile = r / ETILES;
            int n = ntile * 16 + (lane & 15);
            int k0 = kt * 32 + (lane >> 4) * 8;
            bf16x8 o;
#pragma unroll
            for (int j = 0; j < 8; ++j) {
                int k = k0 + j;
                float v = 0.f;
                if (k < IN_DIM) v = (n < 192) ? W_in[k * 192 + n] : loopW_in[k * 192 + (n - 192)];
                o[j] = (short)f2bf(v);
            }
            *(bf16x8*)(wt_e + (size_t)idx * 8) = o;
            return;
        }
        idx -= ENT_CHUNKS;
        if (idx >= RES_CHUNKS) return;
        int lane = idx & 63, r = idx >> 6;
        int kt = r % 12; r /= 12;
        int ntile = r % 12; int l = r / 12;
        const float* W = (l < 12) ? (res_W + (size_t)l * 192 * 192) : W_out;
        const float* L = (l < 12) ? (res_loopW + (size_t)l * 192 * 192) : loopW_out;
        int n = ntile * 16 + (lane & 15);
        int k0 = kt * 32 + (lane >> 4) * 8;
        bf16x8 o;
#pragma unroll
        for (int j = 0; j < 8; ++j) {
            int k2 = k0 + j;
            float v = (k2 < 192) ? W[k2 * 192 + n] : L[(k2 - 192) * 192 + n];
            o[j] = (short)f2bf(v);
        }
        *(bf16x8*)(wt_r + (size_t)idx * 8) = o;
        return;
    }

    int m = blockIdx.x;
    __shared__ int cnt;
    __shared__ int lc[8];
    __shared__ float lv[8];
    if (threadIdx.x == 0) cnt = 0;
    __syncthreads();
    for (int c = threadIdx.x; c < N3V; c += 256) {
        float a = adj[(size_t)m * N3V + c];
        if (a != 0.f) {
            int p = atomicAdd(&cnt, 1);
            if (p < 6) { lc[p] = c; lv[p] = a; }
        }
    }
    __syncthreads();
    if (threadIdx.x == 0) {
        int n = cnt < 6 ? cnt : 6;
        for (int i = 1; i < n; ++i) {
            int ci = lc[i]; float vi = lv[i]; int j = i - 1;
            while (j >= 0 && lc[j] > ci) { lc[j + 1] = lc[j]; lv[j + 1] = lv[j]; --j; }
            lc[j + 1] = ci; lv[j + 1] = vi;
        }
        int ne = 0;
        for (int i = 0; i < 6; ++i) {
            int c = (i < n) ? lc[i] : 0;
            float w = (i < n) ? lv[i] : 0.f;
            cols[m * 6 + i] = c;
            vals[m * 6 + i] = w;
            if (i < n) {
                if (c < N2V) { eidx[m * 12 + ne] = c; ew[m * 12 + ne] = w; ++ne; }
                else {
                    int jj = c - N2V;
                    eidx[m * 12 + ne] = unpool[2 * jj];     ew[m * 12 + ne] = 0.5f * w; ++ne;
                    eidx[m * 12 + ne] = unpool[2 * jj + 1]; ew[m * 12 + ne] = 0.5f * w; ++ne;
                }
            }
        }
        for (; ne < 12; ++ne) { eidx[m * 12 + ne] = 0; ew[m * 12 + ne] = 0.f; }
        if (m < N2V) { sidx[m * 2] = m; sidx[m * 2 + 1] = -1; }
        else {
            int j = m - N2V;
            sidx[m * 2] = unpool[2 * j];
            sidx[m * 2 + 1] = unpool[2 * j + 1];
        }
    }
}

// ---------------------------------------------------------------------------
// F in FRAGMENT layout: F3[rt][kt][lane][8]
// ---------------------------------------------------------------------------
__global__ void build_F3(const float* __restrict__ x, const float* __restrict__ xh,
                         const float* __restrict__ att, ushort* __restrict__ F3)
{
    int rt = blockIdx.x;                       // 0..617
    for (int c = threadIdx.x; c < ETILES * 64; c += 256) {
        int kt = c >> 6, lane = c & 63;
        int row = rt * 16 + (lane & 15);
        int k0 = kt * 32 + (lane >> 4) * 8;
        bf16x8 o;
#pragma unroll
        for (int j = 0; j < 8; ++j) {
            int k = k0 + j;
            float v = 0.f;
            if (k < FEAT) v = x[(size_t)row * FEAT + k];
            else if (k < FEAT + HID) v = xh[(size_t)row * HID + (k - FEAT)];
            else if (k < IN_DIM) v = att[(size_t)row * 8 + (k - FEAT - HID)];
            o[j] = (short)f2bf(v);
        }
        *(bf16x8*)(F3 + ((size_t)(rt * ETILES + kt) * 64 + lane) * 8) = o;
    }
}

// ---------------------------------------------------------------------------
// entry GEMM, K-split x2, fragment layout. 512 thr; 64r x 192c; grid (155,2).
// ---------------------------------------------------------------------------
__global__ __launch_bounds__(512) void gemm_entry(
    const ushort* __restrict__ F3, const ushort* __restrict__ Wt,
    ushort* __restrict__ u2)
{
    __shared__ float part[64 * 192];   // 48 KB

    int tid = threadIdx.x;
    int wave = tid >> 6, lane = tid & 63;
    int kh = wave >> 2, w4 = wave & 3;
    int lr = lane & 15, lkq = lane >> 4;
    int row0 = blockIdx.x * 64;
    int rt0 = blockIdx.x * 4;
    int lnb = w4 * 48;
    int nb = blockIdx.y * 192 + lnb;
    int ntile0 = nb >> 4;
    int tbeg = kh * EHALF, tend = tbeg + EHALF;

    int rts[4];
#pragma unroll
    for (int mt = 0; mt < 4; ++mt) {
        int rt = rt0 + mt;
        rts[mt] = (rt < M2 / 16) ? rt : (M2 / 16 - 1);
    }

    f32x4 acc[4][3];
#pragma unroll
    for (int mt = 0; mt < 4; ++mt)
#pragma unroll
        for (int nt = 0; nt < 3; ++nt) acc[mt][nt] = (f32x4){0.f, 0.f, 0.f, 0.f};

    bf16x8 a0[4], b0[3], a1[4], b1[3];
    auto LD = [&](int t, bf16x8 (&a)[4], bf16x8 (&b)[3]) {
#pragma unroll
        for (int mt = 0; mt < 4; ++mt)
            a[mt] = *(const bf16x8*)(F3 + ((size_t)(rts[mt] * ETILES + t) * 64 + lane) * 8);
#pragma unroll
        for (int nt = 0; nt < 3; ++nt)
            b[nt] = *(const bf16x8*)(Wt + ((size_t)((ntile0 + nt) * ETILES + t) * 64 + lane) * 8);
    };
    auto MM = [&](bf16x8 (&a)[4], bf16x8 (&b)[3]) {
#pragma unroll
        for (int mt = 0; mt < 4; ++mt)
#pragma unroll
            for (int nt = 0; nt < 3; ++nt)
                acc[mt][nt] = __builtin_amdgcn_mfma_f32_16x16x32_bf16(a[mt], b[nt], acc[mt][nt], 0, 0, 0);
    };

    LD(tbeg, a0, b0);
    for (int t = tbeg; t < tend; t += 2) {
        if (t + 1 < tend) LD(t + 1, a1, b1);
        MM(a0, b0);
        if (t + 2 < tend) LD(t + 2, a0, b0);
        if (t + 1 < tend) MM(a1, b1);
    }

    int crow = lkq * 4;
    if (kh == 1) {
#pragma unroll
        for (int mt = 0; mt < 4; ++mt)
#pragma unroll
            for (int r = 0; r < 4; ++r)
#pragma unroll
                for (int nt = 0; nt < 3; ++nt)
                    part[(mt * 16 + crow + r) * 192 + lnb + nt * 16 + lr] = acc[mt][nt][r];
    }
    __syncthreads();
    if (kh == 0) {
#pragma unroll
        for (int mt = 0; mt < 4; ++mt)
#pragma unroll
            for (int r = 0; r < 4; ++r) {
                int orow = row0 + mt * 16 + crow + r;
                if (orow < M2) {
#pragma unroll
                    for (int nt = 0; nt < 3; ++nt) {
                        float s = acc[mt][nt][r] + part[(mt * 16 + crow + r) * 192 + lnb + nt * 16 + lr];
                        u2[(size_t)orow * 384 + nb + nt * 16 + lr] = f2bf(s);
                    }
                }
            }
    }
}

// ---------------------------------------------------------------------------
// entry combine: h = relu( sum_i ew*Pw[eidx] + mid(Pl over sidx) + bias )
// ---------------------------------------------------------------------------
__global__ void combine_entry(const ushort* __restrict__ u2, const int* __restrict__ eidx,
                              const float* __restrict__ ew, const int* __restrict__ sidx,
                              const float* __restrict__ bias, ushort* __restrict__ h)
{
    int lb = xcd_swz(blockIdx.x, gridDim.x);
    int tid = threadIdx.x;
    int rloc = tid / 24, f8 = tid % 24;
    int bm = lb * 8 + rloc;
    if (bm >= MTOT) return;
    int b = bm / N3V, n = bm % N3V;
    const ushort* base = u2 + (size_t)b * N2V * 384;

    float acc[8];
#pragma unroll
    for (int e = 0; e < 8; ++e) acc[e] = 0.f;
#pragma unroll
    for (int i = 0; i < 12; ++i) {
        float w = ew[n * 12 + i];
        bf16x8 v = *(const bf16x8*)(base + (size_t)eidx[n * 12 + i] * 384 + f8 * 8);
#pragma unroll
        for (int e = 0; e < 8; ++e) acc[e] += w * bf2f((ushort)v[e]);
    }
    int p0 = sidx[n * 2], p1 = sidx[n * 2 + 1];
    bf16x8 s0 = *(const bf16x8*)(base + (size_t)p0 * 384 + 192 + f8 * 8);
    if (p1 >= 0) {
        bf16x8 s1 = *(const bf16x8*)(base + (size_t)p1 * 384 + 192 + f8 * 8);
#pragma unroll
        for (int e = 0; e < 8; ++e) acc[e] += 0.5f * (bf2f((ushort)s0[e]) + bf2f((ushort)s1[e]));
    } else {
#pragma unroll
        for (int e = 0; e < 8; ++e) acc[e] += bf2f((ushort)s0[e]);
    }
    bf16x8 o;
#pragma unroll
    for (int e = 0; e < 8; ++e)
        o[e] = (short)f2bf(fmaxf(acc[e] + bias[f8 * 8 + e], 0.f));
    *(bf16x8*)(h + (size_t)bm * 192 + f8 * 8) = o;
}

// ---------------------------------------------------------------------------
// fused res GConv, wave-specialized phase 1, ALL-WAVE phase 2 (r16 structure).
// ---------------------------------------------------------------------------
template <int ACT>
__global__ __launch_bounds__(512) void gconv_fused(
    const ushort* __restrict__ src, const int* __restrict__ cols,
    const float* __restrict__ vals, const ushort* __restrict__ Wt,
    const float* __restrict__ bias, const ushort* __restrict__ hprev,
    ushort* __restrict__ outp)
{
    __shared__ ushort gs[32 * 192];    // 12 KB, XOR-swizzled
    __shared__ float part[32 * 192];   // 24 KB

    int lb = xcd_swz(blockIdx.x, gridDim.x);
    int tid = threadIdx.x;
    int row0 = lb * 32;                // MTOT % 32 == 0

    int wave = tid >> 6, lane = tid & 63;
    int w4 = wave & 3, wm = wave >> 2;
    int lr = lane & 15, lkq = lane >> 4, lk = lkq * 8;
    int nb = w4 * 48;
    int ntile0 = nb >> 4;
    int crow = lkq * 4;

    if (wave >= 4) {
        int rows[2] = { row0 + lr, row0 + 16 + lr };
        f32x4 acc[2][3];
#pragma unroll
        for (int mt = 0; mt < 2; ++mt)
#pragma unroll
            for (int nt = 0; nt < 3; ++nt) acc[mt][nt] = (f32x4){0.f, 0.f, 0.f, 0.f};

        bf16x8 a0[2], b0[3], a1[2], b1[3];
        auto LDs = [&](int t, bf16x8 (&a)[2], bf16x8 (&b)[3]) {
            int kk = t * 32 + lk;
#pragma unroll
            for (int mt = 0; mt < 2; ++mt)
                a[mt] = *(const bf16x8*)(src + (size_t)rows[mt] * 192 + kk);
#pragma unroll
            for (int nt = 0; nt < 3; ++nt)
                b[nt] = *(const bf16x8*)(Wt + ((size_t)((ntile0 + nt) * 12 + 6 + t) * 64 + lane) * 8);
        };
        auto MMs = [&](bf16x8 (&a)[2], bf16x8 (&b)[3]) {
#pragma unroll
            for (int mt = 0; mt < 2; ++mt)
#pragma unroll
                for (int nt = 0; nt < 3; ++nt)
                    acc[mt][nt] = __builtin_amdgcn_mfma_f32_16x16x32_bf16(a[mt], b[nt], acc[mt][nt], 0, 0, 0);
        };
        LDs(0, a0, b0);
#pragma unroll
        for (int t = 0; t < 6; t += 2) {
            if (t + 1 < 6) LDs(t + 1, a1, b1);
            MMs(a0, b0);
            if (t + 2 < 6) LDs(t + 2, a0, b0);
            if (t + 1 < 6) MMs(a1, b1);
        }
#pragma unroll
        for (int mt = 0; mt < 2; ++mt)
#pragma unroll
            for (int r = 0; r < 4; ++r)
#pragma unroll
                for (int nt = 0; nt < 3; ++nt)
                    part[(mt * 16 + crow + r) * 192 + nb + nt * 16 + lr] = acc[mt][nt][r];
    } else {
#pragma unroll
        for (int it = 0; it < 3; ++it) {
            int task = tid + it * 256;
            int r = task / 24, f8 = task % 24;
            int bm = row0 + r;
            int b = bm / N3V, m = bm % N3V;
            const ushort* hb = src + (size_t)b * N3V * 192;
            float ga[8];
#pragma unroll
            for (int e = 0; e < 8; ++e) ga[e] = 0.f;
#pragma unroll
            for (int j = 0; j < 6; ++j) {
                float w = vals[m * 6 + j];
                bf16x8 v = *(const bf16x8*)(hb + (size_t)cols[m * 6 + j] * 192 + f8 * 8);
#pragma unroll
                for (int e = 0; e < 8; ++e) ga[e] += w * bf2f((ushort)v[e]);
            }
            bf16x8 o;
#pragma unroll
            for (int e = 0; e < 8; ++e) o[e] = (short)f2bf(ga[e]);
            int byte = r * 384 + f8 * 16;
            byte ^= (r & 7) << 4;
            *(bf16x8*)((char*)gs + byte) = o;
        }
    }
    __syncthreads();

    // ---- phase 2 (ALL 8 waves): g-half GEMM, m-tile wm, cols nb ----
    {
        f32x4 acc2[3];
#pragma unroll
        for (int nt = 0; nt < 3; ++nt) acc2[nt] = (f32x4){0.f, 0.f, 0.f, 0.f};

        bf16x8 a0, b0[3], a1, b1[3];
        auto LDg = [&](int t, bf16x8 &a, bf16x8 (&b)[3]) {
            int rr = wm * 16 + lr;
            int byte = rr * 384 + t * 64 + lkq * 16;
            byte ^= (rr & 7) << 4;
            a = *(const bf16x8*)((const char*)gs + byte);
#pragma unroll
            for (int nt = 0; nt < 3; ++nt)
                b[nt] = *(const bf16x8*)(Wt + ((size_t)((ntile0 + nt) * 12 + t) * 64 + lane) * 8);
        };
        auto MMg = [&](bf16x8 &a, bf16x8 (&b)[3]) {
#pragma unroll
            for (int nt = 0; nt < 3; ++nt)
                acc2[nt] = __builtin_amdgcn_mfma_f32_16x16x32_bf16(a, b[nt], acc2[nt], 0, 0, 0);
        };
        LDg(0, a0, b0);
#pragma unroll
        for (int t = 0; t < 6; t += 2) {
            if (t + 1 < 6) LDg(t + 1, a1, b1);
            MMg(a0, b0);
            if (t + 2 < 6) LDg(t + 2, a0, b0);
            if (t + 1 < 6) MMg(a1, b1);
        }

#pragma unroll
        for (int r = 0; r < 4; ++r) {
            int orow = row0 + wm * 16 + crow + r;
#pragma unroll
            for (int nt = 0; nt < 3; ++nt) {
                int nn = nb + nt * 16 + lr;
                float s = acc2[nt][r] + part[(wm * 16 + crow + r) * 192 + nn] + bias[nn];
                s = fmaxf(s, 0.f);
                if (ACT) s = 0.5f * (bf2f(hprev[(size_t)orow * 192 + nn]) + s);
                outp[(size_t)orow * 192 + nn] = f2bf(s);
            }
        }
    }
}

// ---------------------------------------------------------------------------
// final head (r15 split form): head_a2 streams y coalesced -> ts[M,6];
// head_b applies the 6-point gather over the tiny 1MB ts buffer.
// ---------------------------------------------------------------------------
__global__ void head_a2(const ushort* __restrict__ y, const float* __restrict__ Wg,
                        const float* __restrict__ loopWg, float* __restrict__ t)
{
    int tid = threadIdx.x;
    int rloc = tid >> 2, sub = tid & 3;
    int bm = blockIdx.x * 64 + rloc;
    if (bm >= MTOT) return;
    float s[6];
#pragma unroll
    for (int c = 0; c < 6; ++c) s[c] = 0.f;
#pragma unroll
    for (int kk = 0; kk < 6; ++kk) {
        int kg = sub * 6 + kk;
        bf16x8 v = *(const bf16x8*)(y + (size_t)bm * 192 + kg * 8);
#pragma unroll
        for (int e = 0; e < 8; ++e) {
            float f = bf2f((ushort)v[e]);
            int k = kg * 8 + e;
            s[0] += f * Wg[k * 3 + 0];
            s[1] += f * Wg[k * 3 + 1];
            s[2] += f * Wg[k * 3 + 2];
            s[3] += f * loopWg[k * 3 + 0];
            s[4] += f * loopWg[k * 3 + 1];
            s[5] += f * loopWg[k * 3 + 2];
        }
    }
#pragma unroll
    for (int o = 1; o <= 2; o <<= 1)
#pragma unroll
        for (int c = 0; c < 6; ++c) s[c] += __shfl_xor(s[c], o);
    if (sub == 0) {
#pragma unroll
        for (int c = 0; c < 6; ++c) t[(size_t)bm * 6 + c] = s[c];
    }
}

__global__ void head_b(const float* __restrict__ t, const int* __restrict__ cols,
                       const float* __restrict__ vals, const float* __restrict__ bg,
                       float* __restrict__ out)
{
    int idx = blockIdx.x * 256 + threadIdx.x;
    if (idx >= MTOT * 3) return;
    int bm = idx / 3, c = idx % 3;
    int b = bm / N3V, m = bm % N3V;
    float s = 0.f;
#pragma unroll
    for (int j = 0; j < 6; ++j)
        s += vals[m * 6 + j] * t[((size_t)b * N3V + cols[m * 6 + j]) * 6 + c];
    s += t[(size_t)bm * 6 + 3 + c] + bg[c];
    out[idx] = s;
}

// ---------------------------------------------------------------------------
extern "C" void kernel_launch(void* const* d_in, const int* in_sizes, int n_in,
                              void* d_out, int out_size, void* d_ws, size_t ws_size,
                              hipStream_t stream)
{
    const float* x        = (const float*)d_in[0];
    const float* x2       = (const float*)d_in[1];
    const float* xh       = (const float*)d_in[2];
    const float* Wq       = (const float*)d_in[3];
    const float* bq       = (const float*)d_in[4];
    const float* Wk       = (const float*)d_in[5];
    const float* bk       = (const float*)d_in[6];
    const float* Wv       = (const float*)d_in[7];
    const float* bv       = (const float*)d_in[8];
    const float* adj      = (const float*)d_in[9];
    const int*   unpool   = (const int*)d_in[10];
    const float* W_in     = (const float*)d_in[11];
    const float* loopW_in = (const float*)d_in[12];
    const float* b_in     = (const float*)d_in[13];
    const float* res_W    = (const float*)d_in[14];
    const float* res_loopW= (const float*)d_in[15];
    const float* res_b    = (const float*)d_in[16];
    const float* W_out    = (const float*)d_in[17];
    const float* loopW_out= (const float*)d_in[18];
    const float* b_out    = (const float*)d_in[19];
    const float* Wg       = (const float*)d_in[20];
    const float* loopWg   = (const float*)d_in[21];
    const float* bg       = (const float*)d_in[22];
    float* out = (float*)d_out;

    char* ws = (char*)d_ws;
    size_t o = 0;
    auto alloc = [&](size_t bytes) { char* p = ws + o; o += (bytes + 255) & ~(size_t)255; return p; };
    float*  att  = (float*)alloc((size_t)M2 * 8 * 4);
    int*    cols = (int*)alloc((size_t)N3V * 6 * 4);
    float*  vals = (float*)alloc((size_t)N3V * 6 * 4);
    int*    eidx = (int*)alloc((size_t)N3V * 12 * 4);
    float*  ewgt = (float*)alloc((size_t)N3V * 12 * 4);
    int*    sidx = (int*)alloc((size_t)N3V * 2 * 4);
    ushort* F3   = (ushort*)alloc((size_t)M2 * KPAD2 * 2);
    ushort* wt_e = (ushort*)alloc((size_t)ENT_CHUNKS * 8 * 2);
    ushort* wt_r = (ushort*)alloc((size_t)RES_CHUNKS * 8 * 2);
    ushort* u2   = (ushort*)alloc((size_t)M2 * 384 * 2);
    ushort* h    = (ushort*)alloc((size_t)MTOT * 192 * 2);
    ushort* h2   = (ushort*)alloc((size_t)MTOT * 192 * 2);
    ushort* y    = (ushort*)alloc((size_t)MTOT * 192 * 2);
    float*  ts   = (float*)alloc((size_t)MTOT * 6 * 4);
    if (ws_size < o) return;

    attn_fused<<<dim3(NB, 39), 256, 0, stream>>>(x2, Wq, bq, Wk, bk, Wv, bv, att);
    prep_all<<<N3V + WT_BLOCKS, 256, 0, stream>>>(adj, unpool, cols, vals, eidx, ewgt, sidx,
        W_in, loopW_in, res_W, res_loopW, W_out, loopW_out, wt_e, wt_r);
    build_F3<<<M2 / 16, 256, 0, stream>>>(x, xh, att, F3);

    // entry: u2 = F @ [W_in | loopW_in]   (M=9888, K=1216, k-split x2)
    gemm_entry<<<dim3((M2 + 63) / 64, 2), 512, 0, stream>>>(F3, wt_e, u2);
    combine_entry<<<(MTOT + 7) / 8, 192, 0, stream>>>(u2, eidx, ewgt, sidx, b_in, h);

    int gg = MTOT / 32;              // 1233
    ushort* cur = h;
    ushort* nxt = h2;
    for (int i = 0; i < 6; ++i) {
        const float* B0 = res_b + (size_t)(i * 2 + 0) * 192;
        const float* B1 = res_b + (size_t)(i * 2 + 1) * 192;
        const ushort* W0 = wt_r + (size_t)(i * 2 + 0) * (12 * 12 * 64 * 8);
        const ushort* W1 = wt_r + (size_t)(i * 2 + 1) * (12 * 12 * 64 * 8);
        gconv_fused<0><<<gg, 512, 0, stream>>>(cur, cols, vals, W0, B0, nullptr, y);
        gconv_fused<1><<<gg, 512, 0, stream>>>(y, cols, vals, W1, B1, cur, nxt);
        ushort* tmp = cur; cur = nxt; nxt = tmp;
    }

    // out conv (relu)
    gconv_fused<0><<<gg, 512, 0, stream>>>(cur, cols, vals,
        wt_r + (size_t)12 * (12 * 12 * 64 * 8), b_out, nullptr, y);

    head_a2<<<(MTOT + 63) / 64, 256, 0, stream>>>(y, Wg, loopWg, ts);
    head_b<<<(MTOT * 3 + 255) / 256, 256, 0, stream>>>(ts, cols, vals, bg, out);
}

// Round 18
// 412.136 us; speedup vs baseline: 1.1013x; 1.0535x over previous
//
#include <hip/hip_runtime.h>
#include <hip/hip_bf16.h>

#define NB 16
#define N2V 618
#define N3V 2466
#define FEAT 963
#define HID 192
#define IN_DIM 1163
#define KPAD2 1216         // 1163 padded to 38*32
#define ETILES 38
#define EHALF 19
#define MTOT (NB * N3V)    // 39456
#define M2   (NB * N2V)    // 9888

typedef __attribute__((ext_vector_type(8))) short bf16x8;
typedef __attribute__((ext_vector_type(4))) float f32x4;

__device__ __forceinline__ float bf2f(ushort u) {
    return __uint_as_float(((unsigned)u) << 16);
}
__device__ __forceinline__ ushort f2bf(float f) {   // round-to-nearest-even
    unsigned u = __float_as_uint(f);
    return (ushort)((u + 0x7FFFu + ((u >> 16) & 1u)) >> 16);
}
// bijective XCD-chunk swizzle (m204)
__device__ __forceinline__ int xcd_swz(int bid, int G) {
    int q = G >> 3, r = G & 7;
    int xcd = bid & 7, slot = bid >> 3;
    return (xcd < r) ? xcd * (q + 1) + slot : r * (q + 1) + (xcd - r) * q + slot;
}

// ---------------------------------------------------------------------------
// fused qkv + attention: block = (batch, 16 queries); 624 blocks.
// ---------------------------------------------------------------------------
__global__ __launch_bounds__(256) void attn_fused(
    const float* __restrict__ x2,
    const float* __restrict__ Wq, const float* __restrict__ bq,
    const float* __restrict__ Wk, const float* __restrict__ bk,
    const float* __restrict__ Wv, const float* __restrict__ bv,
    float* __restrict__ att)
{
    __shared__ float4 kv[N2V * 4];            // K: [0,2*N2V), V: [2*N2V,4*N2V)
    int b = blockIdx.x, qb = blockIdx.y;
    const float* x2b = x2 + (size_t)b * N2V * 3;

    for (int i = threadIdx.x; i < N2V; i += 256) {
        float c0 = x2b[i * 3], c1 = x2b[i * 3 + 1], c2 = x2b[i * 3 + 2];
        float kk[8], vv[8];
#pragma unroll
        for (int d = 0; d < 8; ++d) {
            kk[d] = bk[d] + c0 * Wk[8 + d] + c1 * Wk[16 + d] + c2 * Wk[24 + d];
            vv[d] = bv[d] + c0 * Wv[8 + d] + c1 * Wv[16 + d] + c2 * Wv[24 + d];
        }
        kv[i * 2]     = (float4){kk[0], kk[1], kk[2], kk[3]};
        kv[i * 2 + 1] = (float4){kk[4], kk[5], kk[6], kk[7]};
        kv[N2V * 2 + i * 2]     = (float4){vv[0], vv[1], vv[2], vv[3]};
        kv[N2V * 2 + i * 2 + 1] = (float4){vv[4], vv[5], vv[6], vv[7]};
    }
    __syncthreads();

    int ql = threadIdx.x >> 4, sub = threadIdx.x & 15;
    int qi = qb * 16 + ql;
    bool valid = qi < N2V;
    float qv[8];
#pragma unroll
    for (int d = 0; d < 8; ++d) qv[d] = 0.f;
    if (valid) {
        float c0 = x2b[qi * 3], c1 = x2b[qi * 3 + 1], c2 = x2b[qi * 3 + 2];
#pragma unroll
        for (int d = 0; d < 8; ++d)
            qv[d] = bq[d] + c0 * Wq[8 + d] + c1 * Wq[16 + d] + c2 * Wq[24 + d];
    }

    const float scale = 0.35355339059327373f;
    float m = -3.0e38f, lsum = 0.f, acc[8];
#pragma unroll
    for (int d = 0; d < 8; ++d) acc[d] = 0.f;

    for (int kk = sub; kk < N2V; kk += 16) {
        float4 k0 = kv[kk * 2], k1 = kv[kk * 2 + 1];
        float s = qv[0] * k0.x + qv[1] * k0.y + qv[2] * k0.z + qv[3] * k0.w
                + qv[4] * k1.x + qv[5] * k1.y + qv[6] * k1.z + qv[7] * k1.w;
        s *= scale;
        float nm = fmaxf(m, s);
        float corr = __expf(m - nm);
        float p = __expf(s - nm);
        lsum = lsum * corr + p;
        float4 v0 = kv[N2V * 2 + kk * 2], v1 = kv[N2V * 2 + kk * 2 + 1];
        acc[0] = acc[0] * corr + p * v0.x; acc[1] = acc[1] * corr + p * v0.y;
        acc[2] = acc[2] * corr + p * v0.z; acc[3] = acc[3] * corr + p * v0.w;
        acc[4] = acc[4] * corr + p * v1.x; acc[5] = acc[5] * corr + p * v1.y;
        acc[6] = acc[6] * corr + p * v1.z; acc[7] = acc[7] * corr + p * v1.w;
        m = nm;
    }
#pragma unroll
    for (int o = 1; o <= 8; o <<= 1) {
        float m2 = __shfl_xor(m, o);
        float l2 = __shfl_xor(lsum, o);
        float nm = fmaxf(m, m2);
        float c1 = __expf(m - nm), c2 = __expf(m2 - nm);
        lsum = lsum * c1 + l2 * c2;
#pragma unroll
        for (int d = 0; d < 8; ++d) {
            float a2 = __shfl_xor(acc[d], o);
            acc[d] = acc[d] * c1 + a2 * c2;
        }
        m = nm;
    }
    if (valid && sub == 0) {
#pragma unroll
        for (int d = 0; d < 8; ++d)
            att[((size_t)b * N2V + qi) * 8 + d] = acc[d] / lsum;
    }
}

// ---------------------------------------------------------------------------
// merged prep: blocks 0..N3V-1 = adjacency extraction; blocks >= N3V =
// fragment-layout weight transposes (entry + 13 res layers).
// ---------------------------------------------------------------------------
#define ENT_CHUNKS (24 * 38 * 64)
#define RES_CHUNKS (13 * 12 * 12 * 64)
#define WT_BLOCKS ((ENT_CHUNKS + RES_CHUNKS + 255) / 256)
__global__ void prep_all(const float* __restrict__ adj, const int* __restrict__ unpool,
                         int* __restrict__ cols, float* __restrict__ vals,
                         int* __restrict__ eidx, float* __restrict__ ew,
                         int* __restrict__ sidx,
                         const float* __restrict__ W_in, const float* __restrict__ loopW_in,
                         const float* __restrict__ res_W, const float* __restrict__ res_loopW,
                         const float* __restrict__ W_out, const float* __restrict__ loopW_out,
                         ushort* __restrict__ wt_e, ushort* __restrict__ wt_r)
{
    if (blockIdx.x >= N3V) {
        int idx = (blockIdx.x - N3V) * 256 + threadIdx.x;
        if (idx < ENT_CHUNKS) {
            int lane = idx & 63, r = idx >> 6;
            int kt = r % ETILES, ntile = r / ETILES;
            int n = ntile * 16 + (lane & 15);
            int k0 = kt * 32 + (lane >> 4) * 8;
            bf16x8 o;
#pragma unroll
            for (int j = 0; j < 8; ++j) {
                int k = k0 + j;
                float v = 0.f;
                if (k < IN_DIM) v = (n < 192) ? W_in[k * 192 + n] : loopW_in[k * 192 + (n - 192)];
                o[j] = (short)f2bf(v);
            }
            *(bf16x8*)(wt_e + (size_t)idx * 8) = o;
            return;
        }
        idx -= ENT_CHUNKS;
        if (idx >= RES_CHUNKS) return;
        int lane = idx & 63, r = idx >> 6;
        int kt = r % 12; r /= 12;
        int ntile = r % 12; int l = r / 12;
        const float* W = (l < 12) ? (res_W + (size_t)l * 192 * 192) : W_out;
        const float* L = (l < 12) ? (res_loopW + (size_t)l * 192 * 192) : loopW_out;
        int n = ntile * 16 + (lane & 15);
        int k0 = kt * 32 + (lane >> 4) * 8;
        bf16x8 o;
#pragma unroll
        for (int j = 0; j < 8; ++j) {
            int k2 = k0 + j;
            float v = (k2 < 192) ? W[k2 * 192 + n] : L[(k2 - 192) * 192 + n];
            o[j] = (short)f2bf(v);
        }
        *(bf16x8*)(wt_r + (size_t)idx * 8) = o;
        return;
    }

    int m = blockIdx.x;
    __shared__ int cnt;
    __shared__ int lc[8];
    __shared__ float lv[8];
    if (threadIdx.x == 0) cnt = 0;
    __syncthreads();
    for (int c = threadIdx.x; c < N3V; c += 256) {
        float a = adj[(size_t)m * N3V + c];
        if (a != 0.f) {
            int p = atomicAdd(&cnt, 1);
            if (p < 6) { lc[p] = c; lv[p] = a; }
        }
    }
    __syncthreads();
    if (threadIdx.x == 0) {
        int n = cnt < 6 ? cnt : 6;
        for (int i = 1; i < n; ++i) {
            int ci = lc[i]; float vi = lv[i]; int j = i - 1;
            while (j >= 0 && lc[j] > ci) { lc[j + 1] = lc[j]; lv[j + 1] = lv[j]; --j; }
            lc[j + 1] = ci; lv[j + 1] = vi;
        }
        int ne = 0;
        for (int i = 0; i < 6; ++i) {
            int c = (i < n) ? lc[i] : 0;
            float w = (i < n) ? lv[i] : 0.f;
            cols[m * 6 + i] = c;
            vals[m * 6 + i] = w;
            if (i < n) {
                if (c < N2V) { eidx[m * 12 + ne] = c; ew[m * 12 + ne] = w; ++ne; }
                else {
                    int jj = c - N2V;
                    eidx[m * 12 + ne] = unpool[2 * jj];     ew[m * 12 + ne] = 0.5f * w; ++ne;
                    eidx[m * 12 + ne] = unpool[2 * jj + 1]; ew[m * 12 + ne] = 0.5f * w; ++ne;
                }
            }
        }
        for (; ne < 12; ++ne) { eidx[m * 12 + ne] = 0; ew[m * 12 + ne] = 0.f; }
        if (m < N2V) { sidx[m * 2] = m; sidx[m * 2 + 1] = -1; }
        else {
            int j = m - N2V;
            sidx[m * 2] = unpool[2 * j];
            sidx[m * 2 + 1] = unpool[2 * j + 1];
        }
    }
}

// ---------------------------------------------------------------------------
// F in FRAGMENT layout: F3[rt][kt][lane][8]
// ---------------------------------------------------------------------------
__global__ void build_F3(const float* __restrict__ x, const float* __restrict__ xh,
                         const float* __restrict__ att, ushort* __restrict__ F3)
{
    int rt = blockIdx.x;                       // 0..617
    for (int c = threadIdx.x; c < ETILES * 64; c += 256) {
        int kt = c >> 6, lane = c & 63;
        int row = rt * 16 + (lane & 15);
        int k0 = kt * 32 + (lane >> 4) * 8;
        bf16x8 o;
#pragma unroll
        for (int j = 0; j < 8; ++j) {
            int k = k0 + j;
            float v = 0.f;
            if (k < FEAT) v = x[(size_t)row * FEAT + k];
            else if (k < FEAT + HID) v = xh[(size_t)row * HID + (k - FEAT)];
            else if (k < IN_DIM) v = att[(size_t)row * 8 + (k - FEAT - HID)];
            o[j] = (short)f2bf(v);
        }
        *(bf16x8*)(F3 + ((size_t)(rt * ETILES + kt) * 64 + lane) * 8) = o;
    }
}

// ---------------------------------------------------------------------------
// entry GEMM, K-split x2, fragment layout. 512 thr; 64r x 192c; grid (155,2).
// ---------------------------------------------------------------------------
__global__ __launch_bounds__(512) void gemm_entry(
    const ushort* __restrict__ F3, const ushort* __restrict__ Wt,
    ushort* __restrict__ u2)
{
    __shared__ float part[64 * 192];   // 48 KB

    int tid = threadIdx.x;
    int wave = tid >> 6, lane = tid & 63;
    int kh = wave >> 2, w4 = wave & 3;
    int lr = lane & 15, lkq = lane >> 4;
    int row0 = blockIdx.x * 64;
    int rt0 = blockIdx.x * 4;
    int lnb = w4 * 48;
    int nb = blockIdx.y * 192 + lnb;
    int ntile0 = nb >> 4;
    int tbeg = kh * EHALF, tend = tbeg + EHALF;

    int rts[4];
#pragma unroll
    for (int mt = 0; mt < 4; ++mt) {
        int rt = rt0 + mt;
        rts[mt] = (rt < M2 / 16) ? rt : (M2 / 16 - 1);
    }

    f32x4 acc[4][3];
#pragma unroll
    for (int mt = 0; mt < 4; ++mt)
#pragma unroll
        for (int nt = 0; nt < 3; ++nt) acc[mt][nt] = (f32x4){0.f, 0.f, 0.f, 0.f};

    bf16x8 a0[4], b0[3], a1[4], b1[3];
    auto LD = [&](int t, bf16x8 (&a)[4], bf16x8 (&b)[3]) {
#pragma unroll
        for (int mt = 0; mt < 4; ++mt)
            a[mt] = *(const bf16x8*)(F3 + ((size_t)(rts[mt] * ETILES + t) * 64 + lane) * 8);
#pragma unroll
        for (int nt = 0; nt < 3; ++nt)
            b[nt] = *(const bf16x8*)(Wt + ((size_t)((ntile0 + nt) * ETILES + t) * 64 + lane) * 8);
    };
    auto MM = [&](bf16x8 (&a)[4], bf16x8 (&b)[3]) {
#pragma unroll
        for (int mt = 0; mt < 4; ++mt)
#pragma unroll
            for (int nt = 0; nt < 3; ++nt)
                acc[mt][nt] = __builtin_amdgcn_mfma_f32_16x16x32_bf16(a[mt], b[nt], acc[mt][nt], 0, 0, 0);
    };

    LD(tbeg, a0, b0);
    for (int t = tbeg; t < tend; t += 2) {
        if (t + 1 < tend) LD(t + 1, a1, b1);
        MM(a0, b0);
        if (t + 2 < tend) LD(t + 2, a0, b0);
        if (t + 1 < tend) MM(a1, b1);
    }

    int crow = lkq * 4;
    if (kh == 1) {
#pragma unroll
        for (int mt = 0; mt < 4; ++mt)
#pragma unroll
            for (int r = 0; r < 4; ++r)
#pragma unroll
                for (int nt = 0; nt < 3; ++nt)
                    part[(mt * 16 + crow + r) * 192 + lnb + nt * 16 + lr] = acc[mt][nt][r];
    }
    __syncthreads();
    if (kh == 0) {
#pragma unroll
        for (int mt = 0; mt < 4; ++mt)
#pragma unroll
            for (int r = 0; r < 4; ++r) {
                int orow = row0 + mt * 16 + crow + r;
                if (orow < M2) {
#pragma unroll
                    for (int nt = 0; nt < 3; ++nt) {
                        float s = acc[mt][nt][r] + part[(mt * 16 + crow + r) * 192 + lnb + nt * 16 + lr];
                        u2[(size_t)orow * 384 + nb + nt * 16 + lr] = f2bf(s);
                    }
                }
            }
    }
}

// ---------------------------------------------------------------------------
// entry combine: h = relu( sum_i ew*Pw[eidx] + mid(Pl over sidx) + bias )
// ---------------------------------------------------------------------------
__global__ void combine_entry(const ushort* __restrict__ u2, const int* __restrict__ eidx,
                              const float* __restrict__ ew, const int* __restrict__ sidx,
                              const float* __restrict__ bias, ushort* __restrict__ h)
{
    int lb = xcd_swz(blockIdx.x, gridDim.x);
    int tid = threadIdx.x;
    int rloc = tid / 24, f8 = tid % 24;
    int bm = lb * 8 + rloc;
    if (bm >= MTOT) return;
    int b = bm / N3V, n = bm % N3V;
    const ushort* base = u2 + (size_t)b * N2V * 384;

    float acc[8];
#pragma unroll
    for (int e = 0; e < 8; ++e) acc[e] = 0.f;
#pragma unroll
    for (int i = 0; i < 12; ++i) {
        float w = ew[n * 12 + i];
        bf16x8 v = *(const bf16x8*)(base + (size_t)eidx[n * 12 + i] * 384 + f8 * 8);
#pragma unroll
        for (int e = 0; e < 8; ++e) acc[e] += w * bf2f((ushort)v[e]);
    }
    int p0 = sidx[n * 2], p1 = sidx[n * 2 + 1];
    bf16x8 s0 = *(const bf16x8*)(base + (size_t)p0 * 384 + 192 + f8 * 8);
    if (p1 >= 0) {
        bf16x8 s1 = *(const bf16x8*)(base + (size_t)p1 * 384 + 192 + f8 * 8);
#pragma unroll
        for (int e = 0; e < 8; ++e) acc[e] += 0.5f * (bf2f((ushort)s0[e]) + bf2f((ushort)s1[e]));
    } else {
#pragma unroll
        for (int e = 0; e < 8; ++e) acc[e] += bf2f((ushort)s0[e]);
    }
    bf16x8 o;
#pragma unroll
    for (int e = 0; e < 8; ++e)
        o[e] = (short)f2bf(fmaxf(acc[e] + bias[f8 * 8 + e], 0.f));
    *(bf16x8*)(h + (size_t)bm * 192 + f8 * 8) = o;
}

// ---------------------------------------------------------------------------
// fused res GConv (r15 winner): wave-specialized, single barrier.
//   phase 1: waves 4-7 self-half GEMM (2m x 3n, k-tiles 6..11) -> f32 partials;
//            waves 0-3 gather 768 tasks -> gs (XOR-swizzled).
//   phase 2: waves 0-3 g-half GEMM (2m x 3n, k-tiles 0..5) from LDS,
//            add partials + bias (+residual), store. Waves 4-7 exit.
// ---------------------------------------------------------------------------
template <int ACT>
__global__ __launch_bounds__(512) void gconv_fused(
    const ushort* __restrict__ src, const int* __restrict__ cols,
    const float* __restrict__ vals, const ushort* __restrict__ Wt,
    const float* __restrict__ bias, const ushort* __restrict__ hprev,
    ushort* __restrict__ outp)
{
    __shared__ ushort gs[32 * 192];    // 12 KB, XOR-swizzled
    __shared__ float part[32 * 192];   // 24 KB

    int lb = xcd_swz(blockIdx.x, gridDim.x);
    int tid = threadIdx.x;
    int row0 = lb * 32;                // MTOT % 32 == 0

    int wave = tid >> 6, lane = tid & 63;
    int kh = wave >> 2, w4 = wave & 3;
    int lr = lane & 15, lkq = lane >> 4, lk = lkq * 8;
    int nb = w4 * 48;
    int ntile0 = nb >> 4;
    int rows[2] = { row0 + lr, row0 + 16 + lr };
    int ktb = kh * 6;

    f32x4 acc[2][3];
#pragma unroll
    for (int mt = 0; mt < 2; ++mt)
#pragma unroll
        for (int nt = 0; nt < 3; ++nt) acc[mt][nt] = (f32x4){0.f, 0.f, 0.f, 0.f};

    bf16x8 a0[2], b0[3], a1[2], b1[3];
    auto LDself = [&](int t, bf16x8 (&a)[2], bf16x8 (&b)[3]) {
        int kk = t * 32 + lk;
#pragma unroll
        for (int mt = 0; mt < 2; ++mt)
            a[mt] = *(const bf16x8*)(src + (size_t)rows[mt] * 192 + kk);
#pragma unroll
        for (int nt = 0; nt < 3; ++nt)
            b[nt] = *(const bf16x8*)(Wt + ((size_t)((ntile0 + nt) * 12 + ktb + t) * 64 + lane) * 8);
    };
    auto LDg = [&](int t, bf16x8 (&a)[2], bf16x8 (&b)[3]) {
#pragma unroll
        for (int mt = 0; mt < 2; ++mt) {
            int rr = mt * 16 + lr;
            int byte = rr * 384 + t * 64 + lkq * 16;
            byte ^= (rr & 7) << 4;
            a[mt] = *(const bf16x8*)((const char*)gs + byte);
        }
#pragma unroll
        for (int nt = 0; nt < 3; ++nt)
            b[nt] = *(const bf16x8*)(Wt + ((size_t)((ntile0 + nt) * 12 + ktb + t) * 64 + lane) * 8);
    };
    auto MM = [&](bf16x8 (&a)[2], bf16x8 (&b)[3]) {
#pragma unroll
        for (int mt = 0; mt < 2; ++mt)
#pragma unroll
            for (int nt = 0; nt < 3; ++nt)
                acc[mt][nt] = __builtin_amdgcn_mfma_f32_16x16x32_bf16(a[mt], b[nt], acc[mt][nt], 0, 0, 0);
    };

    int crow = lkq * 4;

    if (kh == 1) {
        // ---- phase 1 (waves 4-7): self-half GEMM (no gather dependency) ----
        LDself(0, a0, b0);
#pragma unroll
        for (int t = 0; t < 6; t += 2) {
            if (t + 1 < 6) LDself(t + 1, a1, b1);
            MM(a0, b0);
            if (t + 2 < 6) LDself(t + 2, a0, b0);
            if (t + 1 < 6) MM(a1, b1);
        }
#pragma unroll
        for (int mt = 0; mt < 2; ++mt)
#pragma unroll
            for (int r = 0; r < 4; ++r)
#pragma unroll
                for (int nt = 0; nt < 3; ++nt)
                    part[(mt * 16 + crow + r) * 192 + nb + nt * 16 + lr] = acc[mt][nt][r];
    } else {
        // ---- phase 1 (waves 0-3): gather 768 tasks over threads 0..255 ----
#pragma unroll
        for (int it = 0; it < 3; ++it) {
            int task = tid + it * 256;
            int r = task / 24, f8 = task % 24;
            int bm = row0 + r;
            int b = bm / N3V, m = bm % N3V;
            const ushort* hb = src + (size_t)b * N3V * 192;
            float ga[8];
#pragma unroll
            for (int e = 0; e < 8; ++e) ga[e] = 0.f;
#pragma unroll
            for (int j = 0; j < 6; ++j) {
                float w = vals[m * 6 + j];
                bf16x8 v = *(const bf16x8*)(hb + (size_t)cols[m * 6 + j] * 192 + f8 * 8);
#pragma unroll
                for (int e = 0; e < 8; ++e) ga[e] += w * bf2f((ushort)v[e]);
            }
            bf16x8 o;
#pragma unroll
            for (int e = 0; e < 8; ++e) o[e] = (short)f2bf(ga[e]);
            int byte = r * 384 + f8 * 16;
            byte ^= (r & 7) << 4;
            *(bf16x8*)((char*)gs + byte) = o;
        }
    }
    __syncthreads();

    if (kh == 0) {
        // ---- phase 2 (waves 0-3): g-half GEMM from LDS ----
        LDg(0, a0, b0);
#pragma unroll
        for (int t = 0; t < 6; t += 2) {
            if (t + 1 < 6) LDg(t + 1, a1, b1);
            MM(a0, b0);
            if (t + 2 < 6) LDg(t + 2, a0, b0);
            if (t + 1 < 6) MM(a1, b1);
        }
#pragma unroll
        for (int mt = 0; mt < 2; ++mt)
#pragma unroll
            for (int r = 0; r < 4; ++r) {
                int orow = row0 + mt * 16 + crow + r;
#pragma unroll
                for (int nt = 0; nt < 3; ++nt) {
                    int nn = nb + nt * 16 + lr;
                    float s = acc[mt][nt][r] + part[(mt * 16 + crow + r) * 192 + nn] + bias[nn];
                    s = fmaxf(s, 0.f);
                    if (ACT) s = 0.5f * (bf2f(hprev[(size_t)orow * 192 + nn]) + s);
                    outp[(size_t)orow * 192 + nn] = f2bf(s);
                }
            }
    }
}

// ---------------------------------------------------------------------------
// final head (split form): head_a2 streams y coalesced -> ts[M,6];
// head_b applies the 6-point gather over the tiny 1MB ts buffer.
// ---------------------------------------------------------------------------
__global__ void head_a2(const ushort* __restrict__ y, const float* __restrict__ Wg,
                        const float* __restrict__ loopWg, float* __restrict__ t)
{
    int tid = threadIdx.x;
    int rloc = tid >> 2, sub = tid & 3;
    int bm = blockIdx.x * 64 + rloc;
    if (bm >= MTOT) return;
    float s[6];
#pragma unroll
    for (int c = 0; c < 6; ++c) s[c] = 0.f;
#pragma unroll
    for (int kk = 0; kk < 6; ++kk) {
        int kg = sub * 6 + kk;
        bf16x8 v = *(const bf16x8*)(y + (size_t)bm * 192 + kg * 8);
#pragma unroll
        for (int e = 0; e < 8; ++e) {
            float f = bf2f((ushort)v[e]);
            int k = kg * 8 + e;
            s[0] += f * Wg[k * 3 + 0];
            s[1] += f * Wg[k * 3 + 1];
            s[2] += f * Wg[k * 3 + 2];
            s[3] += f * loopWg[k * 3 + 0];
            s[4] += f * loopWg[k * 3 + 1];
            s[5] += f * loopWg[k * 3 + 2];
        }
    }
#pragma unroll
    for (int o = 1; o <= 2; o <<= 1)
#pragma unroll
        for (int c = 0; c < 6; ++c) s[c] += __shfl_xor(s[c], o);
    if (sub == 0) {
#pragma unroll
        for (int c = 0; c < 6; ++c) t[(size_t)bm * 6 + c] = s[c];
    }
}

__global__ void head_b(const float* __restrict__ t, const int* __restrict__ cols,
                       const float* __restrict__ vals, const float* __restrict__ bg,
                       float* __restrict__ out)
{
    int idx = blockIdx.x * 256 + threadIdx.x;
    if (idx >= MTOT * 3) return;
    int bm = idx / 3, c = idx % 3;
    int b = bm / N3V, m = bm % N3V;
    float s = 0.f;
#pragma unroll
    for (int j = 0; j < 6; ++j)
        s += vals[m * 6 + j] * t[((size_t)b * N3V + cols[m * 6 + j]) * 6 + c];
    s += t[(size_t)bm * 6 + 3 + c] + bg[c];
    out[idx] = s;
}

// ---------------------------------------------------------------------------
extern "C" void kernel_launch(void* const* d_in, const int* in_sizes, int n_in,
                              void* d_out, int out_size, void* d_ws, size_t ws_size,
                              hipStream_t stream)
{
    const float* x        = (const float*)d_in[0];
    const float* x2       = (const float*)d_in[1];
    const float* xh       = (const float*)d_in[2];
    const float* Wq       = (const float*)d_in[3];
    const float* bq       = (const float*)d_in[4];
    const float* Wk       = (const float*)d_in[5];
    const float* bk       = (const float*)d_in[6];
    const float* Wv       = (const float*)d_in[7];
    const float* bv       = (const float*)d_in[8];
    const float* adj      = (const float*)d_in[9];
    const int*   unpool   = (const int*)d_in[10];
    const float* W_in     = (const float*)d_in[11];
    const float* loopW_in = (const float*)d_in[12];
    const float* b_in     = (const float*)d_in[13];
    const float* res_W    = (const float*)d_in[14];
    const float* res_loopW= (const float*)d_in[15];
    const float* res_b    = (const float*)d_in[16];
    const float* W_out    = (const float*)d_in[17];
    const float* loopW_out= (const float*)d_in[18];
    const float* b_out    = (const float*)d_in[19];
    const float* Wg       = (const float*)d_in[20];
    const float* loopWg   = (const float*)d_in[21];
    const float* bg       = (const float*)d_in[22];
    float* out = (float*)d_out;

    char* ws = (char*)d_ws;
    size_t o = 0;
    auto alloc = [&](size_t bytes) { char* p = ws + o; o += (bytes + 255) & ~(size_t)255; return p; };
    float*  att  = (float*)alloc((size_t)M2 * 8 * 4);
    int*    cols = (int*)alloc((size_t)N3V * 6 * 4);
    float*  vals = (float*)alloc((size_t)N3V * 6 * 4);
    int*    eidx = (int*)alloc((size_t)N3V * 12 * 4);
    float*  ewgt = (float*)alloc((size_t)N3V * 12 * 4);
    int*    sidx = (int*)alloc((size_t)N3V * 2 * 4);
    ushort* F3   = (ushort*)alloc((size_t)M2 * KPAD2 * 2);
    ushort* wt_e = (ushort*)alloc((size_t)ENT_CHUNKS * 8 * 2);
    ushort* wt_r = (ushort*)alloc((size_t)RES_CHUNKS * 8 * 2);
    ushort* u2   = (ushort*)alloc((size_t)M2 * 384 * 2);
    ushort* h    = (ushort*)alloc((size_t)MTOT * 192 * 2);
    ushort* h2   = (ushort*)alloc((size_t)MTOT * 192 * 2);
    ushort* y    = (ushort*)alloc((size_t)MTOT * 192 * 2);
    float*  ts   = (float*)alloc((size_t)MTOT * 6 * 4);
    if (ws_size < o) return;

    attn_fused<<<dim3(NB, 39), 256, 0, stream>>>(x2, Wq, bq, Wk, bk, Wv, bv, att);
    prep_all<<<N3V + WT_BLOCKS, 256, 0, stream>>>(adj, unpool, cols, vals, eidx, ewgt, sidx,
        W_in, loopW_in, res_W, res_loopW, W_out, loopW_out, wt_e, wt_r);
    build_F3<<<M2 / 16, 256, 0, stream>>>(x, xh, att, F3);

    // entry: u2 = F @ [W_in | loopW_in]   (M=9888, K=1216, k-split x2)
    gemm_entry<<<dim3((M2 + 63) / 64, 2), 512, 0, stream>>>(F3, wt_e, u2);
    combine_entry<<<(MTOT + 7) / 8, 192, 0, stream>>>(u2, eidx, ewgt, sidx, b_in, h);

    int gg = MTOT / 32;              // 1233
    ushort* cur = h;
    ushort* nxt = h2;
    for (int i = 0; i < 6; ++i) {
        const float* B0 = res_b + (size_t)(i * 2 + 0) * 192;
        const float* B1 = res_b + (size_t)(i * 2 + 1) * 192;
        const ushort* W0 = wt_r + (size_t)(i * 2 + 0) * (12 * 12 * 64 * 8);
        const ushort* W1 = wt_r + (size_t)(i * 2 + 1) * (12 * 12 * 64 * 8);
        gconv_fused<0><<<gg, 512, 0, stream>>>(cur, cols, vals, W0, B0, nullptr, y);
        gconv_fused<1><<<gg, 512, 0, stream>>>(y, cols, vals, W1, B1, cur, nxt);
        ushort* tmp = cur; cur = nxt; nxt = tmp;
    }

    // out conv (relu)
    gconv_fused<0><<<gg, 512, 0, stream>>>(cur, cols, vals,
        wt_r + (size_t)12 * (12 * 12 * 64 * 8), b_out, nullptr, y);

    head_a2<<<(MTOT + 63) / 64, 256, 0, stream>>>(y, Wg, loopWg, ts);
    head_b<<<(MTOT * 3 + 255) / 256, 256, 0, stream>>>(ts, cols, vals, bg, out);
}